// Round 10
// baseline (357.321 us; speedup 1.0000x reference)
//
#include <hip/hip_runtime.h>
#include <hip/hip_bf16.h>

typedef unsigned short u16;
typedef short bf16x8 __attribute__((ext_vector_type(8)));
typedef float f32x4 __attribute__((ext_vector_type(4)));

#define N_    16
#define CIN   512
#define COUT  512
#define WD    512
#define P_    4096   // 64*64 spatial
#define CC    (COUT * CIN)

// ws layout (bytes)
#define OFF_S   0u
#define OFF_D   32768u
#define OFF_Z   65536u          // 1 KB zero page
#define OFF_WBT 131072u         // 9*512*512*2 = 4718592 B
#define OFF_XB  8388608u        // 16*4096*512*2 = 67108864 B
#define WS_NEED (OFF_XB + 67108864u)

__device__ __forceinline__ u16 f2bf(float f) {
  union { float f; unsigned u; } a; a.f = f;
  unsigned r = a.u + 0x7fffu + ((a.u >> 16) & 1u);   // RNE
  return (u16)(r >> 16);
}

__device__ __forceinline__ void gl_lds16(const u16* g, u16* l) {
  __builtin_amdgcn_global_load_lds(
      (const __attribute__((address_space(1))) void*)g,
      (__attribute__((address_space(3))) void*)l, 16, 0, 0);
}

// ---------- zero page ----------
__global__ void k_zero(float* z) { z[threadIdx.x] = 0.f; }

// ---------- s = w @ affine_w^T + affine_b ----------
__global__ __launch_bounds__(256) void k_affine(const float* __restrict__ w,
                                                const float* __restrict__ aw,
                                                const float* __restrict__ ab,
                                                float* __restrict__ s) {
  int idx = blockIdx.x * 256 + threadIdx.x;       // 16*512
  int n = idx >> 9, c = idx & 511;
  const float4* wr = (const float4*)(w + (size_t)n * WD);
  const float4* ar = (const float4*)(aw + (size_t)c * WD);
  float acc = 0.f;
#pragma unroll 4
  for (int k = 0; k < WD / 4; ++k) {
    float4 a = wr[k], b = ar[k];
    acc += a.x * b.x + a.y * b.y + a.z * b.z + a.w * b.w;
  }
  s[idx] = acc + ab[c];
}

// ---------- d = rsqrt(sum_i s^2 * w2 + 1e-8) ----------
__global__ __launch_bounds__(256) void k_demod(const float* __restrict__ s,
                                               const float* __restrict__ cw,
                                               float* __restrict__ d) {
  __shared__ float w2[CIN];
  int o = blockIdx.x;
  const float* wr = cw + (size_t)o * CIN * 9;
  for (int i = threadIdx.x; i < CIN; i += 256) {
    float acc = 0.f;
#pragma unroll
    for (int t = 0; t < 9; ++t) { float v = wr[i * 9 + t]; acc += v * v; }
    w2[i] = acc;
  }
  __syncthreads();
  int wave = threadIdx.x >> 6, lane = threadIdx.x & 63;
  for (int nn = wave; nn < N_; nn += 4) {
    float acc = 0.f;
    for (int i = lane; i < CIN; i += 64) {
      float sv = s[nn * CIN + i];
      acc += sv * sv * w2[i];
    }
#pragma unroll
    for (int off = 32; off > 0; off >>= 1) acc += __shfl_down(acc, off);
    if (lane == 0) {
      float a = acc + 1e-8f;
      float r = rsqrtf(a);
      r = r * (1.5f - 0.5f * a * r * r);   // Newton refine
      d[nn * COUT + o] = r;
    }
  }
}

// ---------- weights -> bf16, layout [tap][o][i] ----------
__global__ __launch_bounds__(256) void k_wprep(const float* __restrict__ cw,
                                               u16* __restrict__ wbt) {
  int idx = blockIdx.x * 256 + threadIdx.x;
  if (idx >= COUT * CIN * 9) return;
  int t = idx % 9; int oi = idx / 9; int i = oi & 511; int o = oi >> 9;
  wbt[((size_t)t * COUT + o) * CIN + i] = f2bf(cw[idx]);
}

// ---------- x * s -> bf16 NHWC  xb[n][p][c] ----------
__global__ __launch_bounds__(256) void k_xmod(const float* __restrict__ x,
                                              const float* __restrict__ s,
                                              u16* __restrict__ xb) {
  __shared__ float tile[64][65];
  int b = blockIdx.x;                 // 16 * 8 * 64
  int pt = b & 63; int ct = (b >> 6) & 7; int n = b >> 9;
  int c0 = ct * 64, p0 = pt * 64;
  const float* xp = x + ((size_t)n * CIN + c0) * P_ + p0;
  int t = threadIdx.x;
#pragma unroll
  for (int pass = 0; pass < 4; ++pass) {
    int r = pass * 16 + (t >> 4);
    int col4 = (t & 15);
    float4 v = *(const float4*)(xp + (size_t)r * P_ + col4 * 4);
    float sc = s[n * CIN + c0 + r];
    tile[r][col4 * 4 + 0] = v.x * sc;
    tile[r][col4 * 4 + 1] = v.y * sc;
    tile[r][col4 * 4 + 2] = v.z * sc;
    tile[r][col4 * 4 + 3] = v.w * sc;
  }
  __syncthreads();
  int p = t >> 2, cq = (t & 3) * 16;
  union { u16 us[16]; uint4 q[2]; } pk;
#pragma unroll
  for (int j = 0; j < 16; ++j) pk.us[j] = f2bf(tile[cq + j][p]);
  uint4* dst = (uint4*)(xb + ((size_t)n * P_ + p0 + p) * CIN + c0 + cq);
  dst[0] = pk.q[0];
  dst[1] = pk.q[1];
}

// ---------- main conv: implicit GEMM, 256x256 tile, BK=32, ring-4 LDS ----------
// 512 threads = 8 waves (2 wr x 4 wc); per-wave output 128x64.
// m201 dual-barrier phase rhythm. Per tile t, two phases of 16 MFMA:
//  ph0: issue Bf+Af0 reads(8) | issue A-stage(t+3) | vmcnt(6) | bar |
//       lgkm(0) | prio1 16xMFMA acc0 prio0 | bar
//  ph1: issue Af1 reads(4) | issue B-stage(t+3)+advance | bar |
//       lgkm(0) | prio1 16xMFMA acc1 prio0 | bar
// Gate legality: reads of buffer t are legalized by tile t-1's gate (vmcnt(6)
// retires stage(t+1) there) + barrier. Ring-4/depth-3: stage(t+3) writes
// buffer (t-1)&3, whose reads all completed before t-1 ph1's trailing barrier.
__global__ __launch_bounds__(512, 2) void k_conv(const u16* __restrict__ xb,
                                                 const u16* __restrict__ wbt,
                                                 const u16* __restrict__ zp,
                                                 const float* __restrict__ dmod,
                                                 const float* __restrict__ cbias,
                                                 const float* __restrict__ noise,
                                                 const float* __restrict__ nstr,
                                                 float* __restrict__ out) {
  __shared__ u16 smA[4][8192];   // [buf][256 rows x 32 ch] 16 KB each
  __shared__ u16 smB[4][8192];

  // bijective XCD swizzle: nwg=512 -> XCD x gets n in {2x,2x+1}
  int bid = blockIdx.x;
  int wg = (bid & 7) * 64 + (bid >> 3);
  int n = wg >> 5;
  int rem = wg & 31;
  int ob = rem >> 4;            // 0..1   (out-ch block of 256)
  int pb = rem & 15;            // 0..15  (spatial block of 256 = 4 rows)

  int tid = threadIdx.x;
  int wv = tid >> 6, l = tid & 63;
  int wr = wv >> 2, wc = wv & 3;
  int lrow = l & 15, kgrp = l >> 4;
  int prs = kgrp ^ ((lrow >> 1) & 3);          // read phys slot (swizzle)

  // staging constants
  int srow = tid >> 2;                          // 0..127 row within group
  int lslot = (tid & 3) ^ ((tid >> 3) & 3);     // logical k-slot staged
  const u16* xbn = xb + (size_t)n * P_ * CIN;
  int hg[2], wgp[2];
#pragma unroll
  for (int g = 0; g < 2; ++g) {
    int ploc = g * 128 + srow;
    hg[g] = pb * 4 + (ploc >> 6);
    wgp[g] = ploc & 63;
  }
  const u16* srcA_base[2];
#pragma unroll
  for (int g = 0; g < 2; ++g)
    srcA_base[g] = wbt + (size_t)(ob * 256 + g * 128 + srow) * CIN + lslot * 8;

  auto stage_A = [&](int tt) {
    int b = tt & 3;
    int tapn = tt >> 4, cbn = tt & 15;
#pragma unroll
    for (int g = 0; g < 2; ++g) {
      const u16* src = srcA_base[g] + (size_t)tapn * CC + cbn * 32;
      gl_lds16(src, &smA[b][g * 4096 + wv * 512]);
    }
  };
  auto bsrc_for_tap = [&](int tapn, int g) -> const u16* {
    int dh = tapn < 3 ? -1 : (tapn < 6 ? 0 : 1);
    int dw = tapn - (dh + 1) * 3 - 1;
    int hh = hg[g] + dh, ww = wgp[g] + dw;
    bool val = ((unsigned)hh < 64u) && ((unsigned)ww < 64u);
    return val ? (xbn + ((size_t)((hh << 6) + ww)) * CIN + lslot * 8)
               : (zp + lslot * 8);
  };
  auto stage_B = [&](int tt) {
    int b = tt & 3;
    int tapn = tt >> 4, cbn = tt & 15;
#pragma unroll
    for (int g = 0; g < 2; ++g)
      gl_lds16(bsrc_for_tap(tapn, g) + cbn * 32, &smB[b][g * 4096 + wv * 512]);
  };

  f32x4 acc0[4][4], acc1[4][4];
  f32x4 zero = {0.f, 0.f, 0.f, 0.f};
#pragma unroll
  for (int i = 0; i < 4; ++i)
#pragma unroll
    for (int j = 0; j < 4; ++j) { acc0[i][j] = zero; acc1[i][j] = zero; }

  // prologue: stage tiles 0,1,2 (12 gl_lds); confirm stage(0) for t=0 reads
  stage_A(0); stage_B(0);
  stage_A(1); stage_B(1);
  stage_A(2); stage_B(2);
  asm volatile("s_waitcnt vmcnt(8)" ::: "memory");
  __builtin_amdgcn_s_barrier();
  __builtin_amdgcn_sched_barrier(0);

  // rolling source pointers for stage of tile t+3 (init tile 3: tap0, cb3)
  int tap3 = 0, cb3 = 3;
  const u16* rpA[2];
  const u16* rpB[2];
#pragma unroll
  for (int g = 0; g < 2; ++g) {
    rpA[g] = srcA_base[g] + 3 * 32;
    rpB[g] = bsrc_for_tap(0, g) + 3 * 32;
  }

  for (int t = 0; t < 144; ++t) {      // 9 taps * 16 cb
    int b = t & 3;
    int bs = (t + 3) & 3;
    const u16* A = smA[b];
    const u16* B = smB[b];
    bf16x8 Bf[4], Af0[4], Af1[4];

    // ================= phase 0 =================
    // issue reads of buffer t (legalized by gate at t-1 + barrier)
#pragma unroll
    for (int ni = 0; ni < 4; ++ni)
      Bf[ni] = *(const bf16x8*)&B[(wc * 64 + ni * 16 + lrow) * 32 + prs * 8];
#pragma unroll
    for (int mi = 0; mi < 4; ++mi)
      Af0[mi] = *(const bf16x8*)&A[(wr * 128 + mi * 16 + lrow) * 32 + prs * 8];
    __builtin_amdgcn_sched_barrier(0);
    // issue A-stage(t+3)
    if (t <= 140) {
#pragma unroll
      for (int g = 0; g < 2; ++g)
        gl_lds16(rpA[g], &smA[bs][g * 4096 + wv * 512]);
    }
    __builtin_amdgcn_sched_barrier(0);
    // gate: retire stage(t+1)  [outstanding: st(t+1) 4, st(t+2) 4, Ast(t+3) 2]
    if (t <= 140)      asm volatile("s_waitcnt vmcnt(6)" ::: "memory");
    else if (t == 141) asm volatile("s_waitcnt vmcnt(4)" ::: "memory");
    else               asm volatile("s_waitcnt vmcnt(0)" ::: "memory");
    __builtin_amdgcn_s_barrier();
    asm volatile("s_waitcnt lgkmcnt(0)" ::: "memory");
    __builtin_amdgcn_sched_barrier(0);
    __builtin_amdgcn_s_setprio(1);
#pragma unroll
    for (int mi = 0; mi < 4; ++mi)
#pragma unroll
      for (int ni = 0; ni < 4; ++ni)
        acc0[mi][ni] = __builtin_amdgcn_mfma_f32_16x16x32_bf16(
            Af0[mi], Bf[ni], acc0[mi][ni], 0, 0, 0);
    __builtin_amdgcn_s_setprio(0);
    __builtin_amdgcn_s_barrier();
    __builtin_amdgcn_sched_barrier(0);

    // ================= phase 1 =================
#pragma unroll
    for (int mi = 0; mi < 4; ++mi)
      Af1[mi] = *(const bf16x8*)&A[(wr * 128 + 64 + mi * 16 + lrow) * 32 + prs * 8];
    __builtin_amdgcn_sched_barrier(0);
    // issue B-stage(t+3) + pointer advance to t+4
    if (t <= 140) {
#pragma unroll
      for (int g = 0; g < 2; ++g)
        gl_lds16(rpB[g], &smB[bs][g * 4096 + wv * 512]);
      cb3++;
      if (cb3 == 16) {
        cb3 = 0; tap3++;
#pragma unroll
        for (int g = 0; g < 2; ++g) {
          rpA[g] = srcA_base[g] + (size_t)tap3 * CC;
          rpB[g] = bsrc_for_tap(tap3, g);
        }
      } else {
#pragma unroll
        for (int g = 0; g < 2; ++g) { rpA[g] += 32; rpB[g] += 32; }
      }
    }
    __builtin_amdgcn_sched_barrier(0);
    __builtin_amdgcn_s_barrier();
    asm volatile("s_waitcnt lgkmcnt(0)" ::: "memory");
    __builtin_amdgcn_sched_barrier(0);
    __builtin_amdgcn_s_setprio(1);
#pragma unroll
    for (int mi = 0; mi < 4; ++mi)
#pragma unroll
      for (int ni = 0; ni < 4; ++ni)
        acc1[mi][ni] = __builtin_amdgcn_mfma_f32_16x16x32_bf16(
            Af1[mi], Bf[ni], acc1[mi][ni], 0, 0, 0);
    __builtin_amdgcn_s_setprio(0);
    __builtin_amdgcn_s_barrier();
    __builtin_amdgcn_sched_barrier(0);
  }

  // epilogue: demod scale + bias + noise + LeakyReLU(0.2)
  float ns = nstr[0];
  const float* noise_n = noise + (size_t)n * P_;
  float nz[4];
#pragma unroll
  for (int ni = 0; ni < 4; ++ni)
    nz[ni] = noise_n[pb * 256 + wc * 64 + ni * 16 + lrow] * ns;

  auto epi = [&](f32x4 (&A_)[4][4], int qm) {
#pragma unroll
    for (int mi = 0; mi < 4; ++mi) {
      int o0 = ob * 256 + wr * 128 + qm * 64 + mi * 16 + kgrp * 4;
#pragma unroll
      for (int r = 0; r < 4; ++r) {
        int o = o0 + r;
        float dv = dmod[n * COUT + o];
        float bv = cbias[o];
        float* orow = out + ((size_t)(n * COUT + o)) * P_ + pb * 256 + wc * 64;
#pragma unroll
        for (int ni = 0; ni < 4; ++ni) {
          float v = A_[mi][ni][r] * dv + bv + nz[ni];
          orow[ni * 16 + lrow] = v >= 0.f ? v : 0.2f * v;
        }
      }
    }
  };
  epi(acc0, 0);
  epi(acc1, 1);
}

// ---------- fallback (small ws): direct conv ----------
__global__ __launch_bounds__(64) void k_conv_naive(const float* __restrict__ x,
                                                   const float* __restrict__ cw,
                                                   const float* __restrict__ cbias,
                                                   const float* __restrict__ noise,
                                                   const float* __restrict__ nstr,
                                                   const float* __restrict__ s,
                                                   const float* __restrict__ d,
                                                   float* __restrict__ out) {
  int bid = blockIdx.x;                 // 16*512*64 = (n,o,h)
  int h = bid & 63; int o = (bid >> 6) & 511; int n = bid >> 15;
  int wcol = threadIdx.x;
  float acc = 0.f;
  for (int i = 0; i < CIN; ++i) {
    float sv = s[n * CIN + i];
    const float* xrow = x + ((size_t)(n * CIN + i)) * P_;
    const float* wrp = cw + ((size_t)o * CIN + i) * 9;
#pragma unroll
    for (int t = 0; t < 9; ++t) {
      int hh = h + t / 3 - 1, ww = wcol + t % 3 - 1;
      float xv = ((unsigned)hh < 64u && (unsigned)ww < 64u) ? xrow[hh * 64 + ww] : 0.f;
      acc += xv * sv * wrp[t];
    }
  }
  float v = acc * d[n * COUT + o] + cbias[o] + noise[(size_t)n * P_ + h * 64 + wcol] * nstr[0];
  out[((size_t)(n * COUT + o)) * P_ + h * 64 + wcol] = v >= 0.f ? v : 0.2f * v;
}

extern "C" void kernel_launch(void* const* d_in, const int* in_sizes, int n_in,
                              void* d_out, int out_size, void* d_ws, size_t ws_size,
                              hipStream_t stream) {
  const float* x    = (const float*)d_in[0];
  const float* w    = (const float*)d_in[1];
  const float* noise= (const float*)d_in[2];
  const float* aw   = (const float*)d_in[3];
  const float* ab   = (const float*)d_in[4];
  const float* nstr = (const float*)d_in[5];
  const float* cw   = (const float*)d_in[6];
  const float* cb   = (const float*)d_in[7];
  float* out = (float*)d_out;
  char* ws = (char*)d_ws;
  float* s = (float*)(ws + OFF_S);
  float* d = (float*)(ws + OFF_D);

  k_affine<<<(N_ * COUT) / 256, 256, 0, stream>>>(w, aw, ab, s);
  k_demod<<<COUT, 256, 0, stream>>>(s, cw, d);

  if (ws_size >= WS_NEED) {
    u16* zp  = (u16*)(ws + OFF_Z);
    u16* wbt = (u16*)(ws + OFF_WBT);
    u16* xbb = (u16*)(ws + OFF_XB);
    k_zero<<<1, 256, 0, stream>>>((float*)zp);
    k_wprep<<<(COUT * CIN * 9 + 255) / 256, 256, 0, stream>>>(cw, wbt);
    k_xmod<<<N_ * 8 * 64, 256, 0, stream>>>(x, s, xbb);
    k_conv<<<512, 512, 0, stream>>>(xbb, wbt, zp, d, cb, noise, nstr, out);
  } else {
    k_conv_naive<<<N_ * COUT * 64, 64, 0, stream>>>(x, cw, cb, noise, nstr, s, d, out);
  }
}

// Round 11
// 348.931 us; speedup vs baseline: 1.0240x; 1.0240x over previous
//
#include <hip/hip_runtime.h>
#include <hip/hip_bf16.h>

typedef unsigned short u16;
typedef short bf16x8 __attribute__((ext_vector_type(8)));
typedef float f32x4 __attribute__((ext_vector_type(4)));

#define N_    16
#define CIN   512
#define COUT  512
#define WD    512
#define P_    4096   // 64*64 spatial
#define CC    (COUT * CIN)

// ws layout (bytes)
#define OFF_S   0u
#define OFF_D   32768u
#define OFF_Z   65536u          // 1 KB zero page
#define OFF_WBT 131072u         // 9*512*512*2 = 4718592 B
#define OFF_XB  8388608u        // 16*4096*512*2 = 67108864 B
#define WS_NEED (OFF_XB + 67108864u)

__device__ __forceinline__ u16 f2bf(float f) {
  union { float f; unsigned u; } a; a.f = f;
  unsigned r = a.u + 0x7fffu + ((a.u >> 16) & 1u);   // RNE
  return (u16)(r >> 16);
}

__device__ __forceinline__ void gl_lds16(const u16* g, u16* l) {
  __builtin_amdgcn_global_load_lds(
      (const __attribute__((address_space(1))) void*)g,
      (__attribute__((address_space(3))) void*)l, 16, 0, 0);
}

// ---------- zero page ----------
__global__ void k_zero(float* z) { z[threadIdx.x] = 0.f; }

// ---------- s = w @ affine_w^T + affine_b ----------
__global__ __launch_bounds__(256) void k_affine(const float* __restrict__ w,
                                                const float* __restrict__ aw,
                                                const float* __restrict__ ab,
                                                float* __restrict__ s) {
  int idx = blockIdx.x * 256 + threadIdx.x;       // 16*512
  int n = idx >> 9, c = idx & 511;
  const float4* wr = (const float4*)(w + (size_t)n * WD);
  const float4* ar = (const float4*)(aw + (size_t)c * WD);
  float acc = 0.f;
#pragma unroll 4
  for (int k = 0; k < WD / 4; ++k) {
    float4 a = wr[k], b = ar[k];
    acc += a.x * b.x + a.y * b.y + a.z * b.z + a.w * b.w;
  }
  s[idx] = acc + ab[c];
}

// ---------- d = rsqrt(sum_i s^2 * w2 + 1e-8) ----------
__global__ __launch_bounds__(256) void k_demod(const float* __restrict__ s,
                                               const float* __restrict__ cw,
                                               float* __restrict__ d) {
  __shared__ float w2[CIN];
  int o = blockIdx.x;
  const float* wr = cw + (size_t)o * CIN * 9;
  for (int i = threadIdx.x; i < CIN; i += 256) {
    float acc = 0.f;
#pragma unroll
    for (int t = 0; t < 9; ++t) { float v = wr[i * 9 + t]; acc += v * v; }
    w2[i] = acc;
  }
  __syncthreads();
  int wave = threadIdx.x >> 6, lane = threadIdx.x & 63;
  for (int nn = wave; nn < N_; nn += 4) {
    float acc = 0.f;
    for (int i = lane; i < CIN; i += 64) {
      float sv = s[nn * CIN + i];
      acc += sv * sv * w2[i];
    }
#pragma unroll
    for (int off = 32; off > 0; off >>= 1) acc += __shfl_down(acc, off);
    if (lane == 0) {
      float a = acc + 1e-8f;
      float r = rsqrtf(a);
      r = r * (1.5f - 0.5f * a * r * r);   // Newton refine
      d[nn * COUT + o] = r;
    }
  }
}

// ---------- weights -> bf16, layout [tap][o][i] ----------
__global__ __launch_bounds__(256) void k_wprep(const float* __restrict__ cw,
                                               u16* __restrict__ wbt) {
  int idx = blockIdx.x * 256 + threadIdx.x;
  if (idx >= COUT * CIN * 9) return;
  int t = idx % 9; int oi = idx / 9; int i = oi & 511; int o = oi >> 9;
  wbt[((size_t)t * COUT + o) * CIN + i] = f2bf(cw[idx]);
}

// ---------- x * s -> bf16 NHWC  xb[n][p][c] ----------
__global__ __launch_bounds__(256) void k_xmod(const float* __restrict__ x,
                                              const float* __restrict__ s,
                                              u16* __restrict__ xb) {
  __shared__ float tile[64][65];
  int b = blockIdx.x;                 // 16 * 8 * 64
  int pt = b & 63; int ct = (b >> 6) & 7; int n = b >> 9;
  int c0 = ct * 64, p0 = pt * 64;
  const float* xp = x + ((size_t)n * CIN + c0) * P_ + p0;
  int t = threadIdx.x;
#pragma unroll
  for (int pass = 0; pass < 4; ++pass) {
    int r = pass * 16 + (t >> 4);
    int col4 = (t & 15);
    float4 v = *(const float4*)(xp + (size_t)r * P_ + col4 * 4);
    float sc = s[n * CIN + c0 + r];
    tile[r][col4 * 4 + 0] = v.x * sc;
    tile[r][col4 * 4 + 1] = v.y * sc;
    tile[r][col4 * 4 + 2] = v.z * sc;
    tile[r][col4 * 4 + 3] = v.w * sc;
  }
  __syncthreads();
  int p = t >> 2, cq = (t & 3) * 16;
  union { u16 us[16]; uint4 q[2]; } pk;
#pragma unroll
  for (int j = 0; j < 16; ++j) pk.us[j] = f2bf(tile[cq + j][p]);
  uint4* dst = (uint4*)(xb + ((size_t)n * P_ + p0 + p) * CIN + c0 + cq);
  dst[0] = pk.q[0];
  dst[1] = pk.q[1];
}

// ---------- main conv: implicit GEMM, 256x256 tile, BK=32, ring-3 LDS ----------
// 256 threads = 4 waves (2 wr x 2 wc); per-wave output 128x128 (acc 8x8 f32x4
// = 256 regs, 1 wave/SIMD — hand-asm register regime, __launch_bounds__(256,1)).
// LDS read redundancy drops to 2x/2x: 16 b128 reads/wave/tile (64/CU vs 96
// for the 8-wave shape). Per tile: gate {vmcnt(8); barrier}; 16 ds_reads
// (B0..7,A0..3 | A4..7); stage(t+2) = 8 gl_lds; lgkm(4) -> 32 MFMA (mi0..3);
// lgkm(0) -> 32 MFMA (mi4..7). vmcnt never drains mid-loop.
__global__ __launch_bounds__(256, 1) void k_conv(const u16* __restrict__ xb,
                                                 const u16* __restrict__ wbt,
                                                 const u16* __restrict__ zp,
                                                 const float* __restrict__ dmod,
                                                 const float* __restrict__ cbias,
                                                 const float* __restrict__ noise,
                                                 const float* __restrict__ nstr,
                                                 float* __restrict__ out) {
  __shared__ u16 smA[3][8192];   // [buf][256 rows x 32 ch] 16 KB each
  __shared__ u16 smB[3][8192];

  // bijective XCD swizzle: nwg=512 -> XCD x gets n in {2x,2x+1}
  int bid = blockIdx.x;
  int wg = (bid & 7) * 64 + (bid >> 3);
  int n = wg >> 5;
  int rem = wg & 31;
  int ob = rem >> 4;            // 0..1   (out-ch block of 256)
  int pb = rem & 15;            // 0..15  (spatial block of 256 = 4 rows)

  int tid = threadIdx.x;
  int wv = tid >> 6, l = tid & 63;
  int wr = wv >> 1, wc = wv & 1;
  int lrow = l & 15, kgrp = l >> 4;
  int prs = kgrp ^ ((lrow >> 1) & 3);          // read phys slot (swizzle)

  // staging constants: wave wv stages rows [wv*64, wv*64+64) of A and B,
  // 4 instrs of 16 rows each; thread covers row (l>>2), phys slot l&3.
  int srl = l >> 2;                             // 0..15 row within instr
  int lslot = (l & 3) ^ ((l >> 3) & 3);         // logical k-slot staged
  const u16* xbn = xb + (size_t)n * P_ * CIN;

  int hgj[4], wgj[4];
#pragma unroll
  for (int j = 0; j < 4; ++j) {
    int rB = wv * 64 + j * 16 + srl;            // 0..255
    hgj[j] = pb * 4 + (rB >> 6);
    wgj[j] = rB & 63;
  }
  const u16* srcA_base[4];
#pragma unroll
  for (int j = 0; j < 4; ++j)
    srcA_base[j] = wbt + (size_t)(ob * 256 + wv * 64 + j * 16 + srl) * CIN + lslot * 8;

  auto bsrc_for_tap = [&](int tapn, int j) -> const u16* {
    int dh = tapn < 3 ? -1 : (tapn < 6 ? 0 : 1);
    int dw = tapn - (dh + 1) * 3 - 1;
    int hh = hgj[j] + dh, ww = wgj[j] + dw;
    bool val = ((unsigned)hh < 64u) && ((unsigned)ww < 64u);
    return val ? (xbn + ((size_t)((hh << 6) + ww)) * CIN + lslot * 8)
               : (zp + lslot * 8);
  };

  f32x4 acc[8][8];
  f32x4 zero = {0.f, 0.f, 0.f, 0.f};
#pragma unroll
  for (int i = 0; i < 8; ++i)
#pragma unroll
    for (int j = 0; j < 8; ++j) acc[i][j] = zero;

  // prologue: stage tiles 0 (buf0) and 1 (buf1): per tile 4 A + 4 B gl_lds
#pragma unroll
  for (int tt = 0; tt < 2; ++tt) {
#pragma unroll
    for (int j = 0; j < 4; ++j)
      gl_lds16(srcA_base[j] + tt * 32, &smA[tt][(wv * 64 + j * 16) * 32]);
#pragma unroll
    for (int j = 0; j < 4; ++j)
      gl_lds16(bsrc_for_tap(0, j) + tt * 32, &smB[tt][(wv * 64 + j * 16) * 32]);
  }

  // rolling source state for stage of tile t+2 (init tile 2: tap0, cb2)
  int tap3 = 0, cb3 = 2;
  int aoff = 2 * 32;                            // tap3*CC + cb3*32
  const u16* rpB[4];
#pragma unroll
  for (int j = 0; j < 4; ++j) rpB[j] = bsrc_for_tap(0, j) + 2 * 32;

  int bcur = 0, bstg = 2;
  for (int t = 0; t < 144; ++t) {      // 9 taps * 16 cb
    // gate: stage(t) retired everywhere after barrier (stage(t+1)=8 in flight)
    if (t <= 142) asm volatile("s_waitcnt vmcnt(8)" ::: "memory");
    else          asm volatile("s_waitcnt vmcnt(0)" ::: "memory");
    __builtin_amdgcn_s_barrier();
    __builtin_amdgcn_sched_barrier(0);

    const u16* A = smA[bcur];
    const u16* B = smB[bcur];

    // ---- issue all 16 fragment reads; order pinned: B0..7,A0..3 | A4..7 ----
    bf16x8 Bf[8], Af[8];
#pragma unroll
    for (int ni = 0; ni < 8; ++ni)
      Bf[ni] = *(const bf16x8*)&B[(wc * 128 + ni * 16 + lrow) * 32 + prs * 8];
#pragma unroll
    for (int mi = 0; mi < 4; ++mi)
      Af[mi] = *(const bf16x8*)&A[(wr * 128 + mi * 16 + lrow) * 32 + prs * 8];
    __builtin_amdgcn_sched_barrier(0);
#pragma unroll
    for (int mi = 4; mi < 8; ++mi)
      Af[mi] = *(const bf16x8*)&A[(wr * 128 + mi * 16 + lrow) * 32 + prs * 8];
    __builtin_amdgcn_sched_barrier(0);

    // ---- stage tile t+2 (8 gl_lds, vmcnt only) + pointer advance ----
    if (t <= 141) {
#pragma unroll
      for (int j = 0; j < 4; ++j)
        gl_lds16(srcA_base[j] + aoff, &smA[bstg][(wv * 64 + j * 16) * 32]);
#pragma unroll
      for (int j = 0; j < 4; ++j)
        gl_lds16(rpB[j], &smB[bstg][(wv * 64 + j * 16) * 32]);
      cb3++;
      if (cb3 == 16) {
        cb3 = 0; tap3++;
        aoff = tap3 * CC;
#pragma unroll
        for (int j = 0; j < 4; ++j) rpB[j] = bsrc_for_tap(tap3, j);
      } else {
        aoff += 32;
#pragma unroll
        for (int j = 0; j < 4; ++j) rpB[j] += 32;
      }
    }
    __builtin_amdgcn_sched_barrier(0);

    // ---- wait for B0..7+A0..3 (A4..7 land under the first MFMA cluster) ----
    asm volatile("s_waitcnt lgkmcnt(4)" ::: "memory");
    __builtin_amdgcn_sched_barrier(0);
    __builtin_amdgcn_s_setprio(1);
#pragma unroll
    for (int mi = 0; mi < 4; ++mi)
#pragma unroll
      for (int ni = 0; ni < 8; ++ni)
        acc[mi][ni] = __builtin_amdgcn_mfma_f32_16x16x32_bf16(
            Af[mi], Bf[ni], acc[mi][ni], 0, 0, 0);
    __builtin_amdgcn_s_setprio(0);

    asm volatile("s_waitcnt lgkmcnt(0)" ::: "memory");
    __builtin_amdgcn_sched_barrier(0);
    __builtin_amdgcn_s_setprio(1);
#pragma unroll
    for (int mi = 4; mi < 8; ++mi)
#pragma unroll
      for (int ni = 0; ni < 8; ++ni)
        acc[mi][ni] = __builtin_amdgcn_mfma_f32_16x16x32_bf16(
            Af[mi], Bf[ni], acc[mi][ni], 0, 0, 0);
    __builtin_amdgcn_s_setprio(0);

    bcur = (bcur == 2) ? 0 : bcur + 1;
    bstg = (bstg == 2) ? 0 : bstg + 1;
  }

  // epilogue: demod scale + bias + noise + LeakyReLU(0.2)
  float ns = nstr[0];
  const float* noise_n = noise + (size_t)n * P_;
  float nz[8];
#pragma unroll
  for (int ni = 0; ni < 8; ++ni)
    nz[ni] = noise_n[pb * 256 + wc * 128 + ni * 16 + lrow] * ns;

#pragma unroll
  for (int mi = 0; mi < 8; ++mi) {
    int o0 = ob * 256 + wr * 128 + mi * 16 + kgrp * 4;
#pragma unroll
    for (int r = 0; r < 4; ++r) {
      int o = o0 + r;
      float dv = dmod[n * COUT + o];
      float bv = cbias[o];
      float* orow = out + ((size_t)(n * COUT + o)) * P_ + pb * 256 + wc * 128;
#pragma unroll
      for (int ni = 0; ni < 8; ++ni) {
        float v = acc[mi][ni][r] * dv + bv + nz[ni];
        orow[ni * 16 + lrow] = v >= 0.f ? v : 0.2f * v;
      }
    }
  }
}

// ---------- fallback (small ws): direct conv ----------
__global__ __launch_bounds__(64) void k_conv_naive(const float* __restrict__ x,
                                                   const float* __restrict__ cw,
                                                   const float* __restrict__ cbias,
                                                   const float* __restrict__ noise,
                                                   const float* __restrict__ nstr,
                                                   const float* __restrict__ s,
                                                   const float* __restrict__ d,
                                                   float* __restrict__ out) {
  int bid = blockIdx.x;                 // 16*512*64 = (n,o,h)
  int h = bid & 63; int o = (bid >> 6) & 511; int n = bid >> 15;
  int wcol = threadIdx.x;
  float acc = 0.f;
  for (int i = 0; i < CIN; ++i) {
    float sv = s[n * CIN + i];
    const float* xrow = x + ((size_t)(n * CIN + i)) * P_;
    const float* wrp = cw + ((size_t)o * CIN + i) * 9;
#pragma unroll
    for (int t = 0; t < 9; ++t) {
      int hh = h + t / 3 - 1, ww = wcol + t % 3 - 1;
      float xv = ((unsigned)hh < 64u && (unsigned)ww < 64u) ? xrow[hh * 64 + ww] : 0.f;
      acc += xv * sv * wrp[t];
    }
  }
  float v = acc * d[n * COUT + o] + cbias[o] + noise[(size_t)n * P_ + h * 64 + wcol] * nstr[0];
  out[((size_t)(n * COUT + o)) * P_ + h * 64 + wcol] = v >= 0.f ? v : 0.2f * v;
}

extern "C" void kernel_launch(void* const* d_in, const int* in_sizes, int n_in,
                              void* d_out, int out_size, void* d_ws, size_t ws_size,
                              hipStream_t stream) {
  const float* x    = (const float*)d_in[0];
  const float* w    = (const float*)d_in[1];
  const float* noise= (const float*)d_in[2];
  const float* aw   = (const float*)d_in[3];
  const float* ab   = (const float*)d_in[4];
  const float* nstr = (const float*)d_in[5];
  const float* cw   = (const float*)d_in[6];
  const float* cb   = (const float*)d_in[7];
  float* out = (float*)d_out;
  char* ws = (char*)d_ws;
  float* s = (float*)(ws + OFF_S);
  float* d = (float*)(ws + OFF_D);

  k_affine<<<(N_ * COUT) / 256, 256, 0, stream>>>(w, aw, ab, s);
  k_demod<<<COUT, 256, 0, stream>>>(s, cw, d);

  if (ws_size >= WS_NEED) {
    u16* zp  = (u16*)(ws + OFF_Z);
    u16* wbt = (u16*)(ws + OFF_WBT);
    u16* xbb = (u16*)(ws + OFF_XB);
    k_zero<<<1, 256, 0, stream>>>((float*)zp);
    k_wprep<<<(COUT * CIN * 9 + 255) / 256, 256, 0, stream>>>(cw, wbt);
    k_xmod<<<N_ * 8 * 64, 256, 0, stream>>>(x, s, xbb);
    k_conv<<<512, 256, 0, stream>>>(xbb, wbt, zp, d, cb, noise, nstr, out);
  } else {
    k_conv_naive<<<N_ * COUT * 64, 64, 0, stream>>>(x, cw, cb, noise, nstr, s, d, out);
  }
}

// Round 12
// 339.294 us; speedup vs baseline: 1.0531x; 1.0284x over previous
//
#include <hip/hip_runtime.h>
#include <hip/hip_bf16.h>

typedef unsigned short u16;
typedef short bf16x8 __attribute__((ext_vector_type(8)));
typedef float f32x4 __attribute__((ext_vector_type(4)));

#define N_    16
#define CIN   512
#define COUT  512
#define WD    512
#define P_    4096   // 64*64 spatial
#define CC    (COUT * CIN)

// ws layout (bytes)
#define OFF_S   0u
#define OFF_D   32768u
#define OFF_Z   65536u          // 1 KB zero page
#define OFF_WBT 131072u         // 9*512*512*2 = 4718592 B
#define OFF_XB  8388608u        // 16*4096*512*2 = 67108864 B
#define WS_NEED (OFF_XB + 67108864u)

__device__ __forceinline__ u16 f2bf(float f) {
  union { float f; unsigned u; } a; a.f = f;
  unsigned r = a.u + 0x7fffu + ((a.u >> 16) & 1u);   // RNE
  return (u16)(r >> 16);
}

__device__ __forceinline__ void gl_lds16(const u16* g, u16* l) {
  __builtin_amdgcn_global_load_lds(
      (const __attribute__((address_space(1))) void*)g,
      (__attribute__((address_space(3))) void*)l, 16, 0, 0);
}

// ---------- zero page ----------
__global__ void k_zero(float* z) { z[threadIdx.x] = 0.f; }

// ---------- s = w @ affine_w^T + affine_b ----------
__global__ __launch_bounds__(256) void k_affine(const float* __restrict__ w,
                                                const float* __restrict__ aw,
                                                const float* __restrict__ ab,
                                                float* __restrict__ s) {
  int idx = blockIdx.x * 256 + threadIdx.x;       // 16*512
  int n = idx >> 9, c = idx & 511;
  const float4* wr = (const float4*)(w + (size_t)n * WD);
  const float4* ar = (const float4*)(aw + (size_t)c * WD);
  float acc = 0.f;
#pragma unroll 4
  for (int k = 0; k < WD / 4; ++k) {
    float4 a = wr[k], b = ar[k];
    acc += a.x * b.x + a.y * b.y + a.z * b.z + a.w * b.w;
  }
  s[idx] = acc + ab[c];
}

// ---------- d = rsqrt(sum_i s^2 * w2 + 1e-8) ----------
__global__ __launch_bounds__(256) void k_demod(const float* __restrict__ s,
                                               const float* __restrict__ cw,
                                               float* __restrict__ d) {
  __shared__ float w2[CIN];
  int o = blockIdx.x;
  const float* wr = cw + (size_t)o * CIN * 9;
  for (int i = threadIdx.x; i < CIN; i += 256) {
    float acc = 0.f;
#pragma unroll
    for (int t = 0; t < 9; ++t) { float v = wr[i * 9 + t]; acc += v * v; }
    w2[i] = acc;
  }
  __syncthreads();
  int wave = threadIdx.x >> 6, lane = threadIdx.x & 63;
  for (int nn = wave; nn < N_; nn += 4) {
    float acc = 0.f;
    for (int i = lane; i < CIN; i += 64) {
      float sv = s[nn * CIN + i];
      acc += sv * sv * w2[i];
    }
#pragma unroll
    for (int off = 32; off > 0; off >>= 1) acc += __shfl_down(acc, off);
    if (lane == 0) {
      float a = acc + 1e-8f;
      float r = rsqrtf(a);
      r = r * (1.5f - 0.5f * a * r * r);   // Newton refine
      d[nn * COUT + o] = r;
    }
  }
}

// ---------- weights -> bf16, layout [tap][o][i] ----------
__global__ __launch_bounds__(256) void k_wprep(const float* __restrict__ cw,
                                               u16* __restrict__ wbt) {
  int idx = blockIdx.x * 256 + threadIdx.x;
  if (idx >= COUT * CIN * 9) return;
  int t = idx % 9; int oi = idx / 9; int i = oi & 511; int o = oi >> 9;
  wbt[((size_t)t * COUT + o) * CIN + i] = f2bf(cw[idx]);
}

// ---------- x * s -> bf16 NHWC  xb[n][p][c] ----------
__global__ __launch_bounds__(256) void k_xmod(const float* __restrict__ x,
                                              const float* __restrict__ s,
                                              u16* __restrict__ xb) {
  __shared__ float tile[64][65];
  int b = blockIdx.x;                 // 16 * 8 * 64
  int pt = b & 63; int ct = (b >> 6) & 7; int n = b >> 9;
  int c0 = ct * 64, p0 = pt * 64;
  const float* xp = x + ((size_t)n * CIN + c0) * P_ + p0;
  int t = threadIdx.x;
#pragma unroll
  for (int pass = 0; pass < 4; ++pass) {
    int r = pass * 16 + (t >> 4);
    int col4 = (t & 15);
    float4 v = *(const float4*)(xp + (size_t)r * P_ + col4 * 4);
    float sc = s[n * CIN + c0 + r];
    tile[r][col4 * 4 + 0] = v.x * sc;
    tile[r][col4 * 4 + 1] = v.y * sc;
    tile[r][col4 * 4 + 2] = v.z * sc;
    tile[r][col4 * 4 + 3] = v.w * sc;
  }
  __syncthreads();
  int p = t >> 2, cq = (t & 3) * 16;
  union { u16 us[16]; uint4 q[2]; } pk;
#pragma unroll
  for (int j = 0; j < 16; ++j) pk.us[j] = f2bf(tile[cq + j][p]);
  uint4* dst = (uint4*)(xb + ((size_t)n * P_ + p0 + p) * CIN + c0 + cq);
  dst[0] = pk.q[0];
  dst[1] = pk.q[1];
}

// ---------- main conv: implicit GEMM, 256x256 tile, BK=32, ring-4 LDS ----------
// 512 threads = 8 waves (2 wr x 4 wc); per-wave output 128x64.
// R4 structure + per-column counted lgkm waits: reads issued in order
// Af0[0..3], Bf[0..3], Af1[0..3]; MFMA column ni gates on lgkmcnt(7-ni)
// (first cluster starts after 5 of 12 reads); acc1 gates on lgkmcnt(0).
// MFMA stream advances in lock-step with the LDS read stream instead of
// waiting for the whole per-wave read burst. One barrier / 32 MFMA;
// vmcnt(8) gate, ring-4 depth-3 staging (unchanged from R4).
__global__ __launch_bounds__(512, 2) void k_conv(const u16* __restrict__ xb,
                                                 const u16* __restrict__ wbt,
                                                 const u16* __restrict__ zp,
                                                 const float* __restrict__ dmod,
                                                 const float* __restrict__ cbias,
                                                 const float* __restrict__ noise,
                                                 const float* __restrict__ nstr,
                                                 float* __restrict__ out) {
  __shared__ u16 smA[4][8192];   // [buf][256 rows x 32 ch] 16 KB each
  __shared__ u16 smB[4][8192];

  // bijective XCD swizzle: nwg=512 -> XCD x gets n in {2x,2x+1}
  int bid = blockIdx.x;
  int wg = (bid & 7) * 64 + (bid >> 3);
  int n = wg >> 5;
  int rem = wg & 31;
  int ob = rem >> 4;            // 0..1   (out-ch block of 256)
  int pb = rem & 15;            // 0..15  (spatial block of 256 = 4 rows)

  int tid = threadIdx.x;
  int wv = tid >> 6, l = tid & 63;
  int wr = wv >> 2, wc = wv & 3;
  int lrow = l & 15, kgrp = l >> 4;
  int prs = kgrp ^ ((lrow >> 1) & 3);          // read phys slot (swizzle)

  // staging constants
  int srow = tid >> 2;                          // 0..127 row within group
  int lslot = (tid & 3) ^ ((tid >> 3) & 3);     // logical k-slot staged
  const u16* xbn = xb + (size_t)n * P_ * CIN;
  int hg[2], wgp[2];
#pragma unroll
  for (int g = 0; g < 2; ++g) {
    int ploc = g * 128 + srow;
    hg[g] = pb * 4 + (ploc >> 6);
    wgp[g] = ploc & 63;
  }
  const u16* srcA_base[2];
#pragma unroll
  for (int g = 0; g < 2; ++g)
    srcA_base[g] = wbt + (size_t)(ob * 256 + g * 128 + srow) * CIN + lslot * 8;

  // from-scratch stagers (prologue only)
  auto stage_A = [&](int tt) {
    int b = tt & 3;
    int tapn = tt >> 4, cbn = tt & 15;
#pragma unroll
    for (int g = 0; g < 2; ++g) {
      const u16* src = srcA_base[g] + (size_t)tapn * CC + cbn * 32;
      gl_lds16(src, &smA[b][g * 4096 + wv * 512]);
    }
  };
  auto bsrc_for_tap = [&](int tapn, int g) -> const u16* {
    int dh = tapn < 3 ? -1 : (tapn < 6 ? 0 : 1);
    int dw = tapn - (dh + 1) * 3 - 1;
    int hh = hg[g] + dh, ww = wgp[g] + dw;
    bool val = ((unsigned)hh < 64u) && ((unsigned)ww < 64u);
    return val ? (xbn + ((size_t)((hh << 6) + ww)) * CIN + lslot * 8)
               : (zp + lslot * 8);
  };
  auto stage_B = [&](int tt) {
    int b = tt & 3;
    int tapn = tt >> 4, cbn = tt & 15;
#pragma unroll
    for (int g = 0; g < 2; ++g)
      gl_lds16(bsrc_for_tap(tapn, g) + cbn * 32, &smB[b][g * 4096 + wv * 512]);
  };

  f32x4 acc0[4][4], acc1[4][4];
  f32x4 zero = {0.f, 0.f, 0.f, 0.f};
#pragma unroll
  for (int i = 0; i < 4; ++i)
#pragma unroll
    for (int j = 0; j < 4; ++j) { acc0[i][j] = zero; acc1[i][j] = zero; }

  // prologue: stage tiles 0,1,2 (12 loads in flight; 4 per tile: A then B)
  stage_A(0); stage_B(0);
  stage_A(1); stage_B(1);
  stage_A(2); stage_B(2);

  // rolling source pointers for tile t+3 (init: tile 3 -> tap 0, cb 3)
  int tap3 = 0, cb3 = 3;
  const u16* rpA[2];
  const u16* rpB[2];
#pragma unroll
  for (int g = 0; g < 2; ++g) {
    rpA[g] = srcA_base[g] + 3 * 32;
    rpB[g] = bsrc_for_tap(0, g) + 3 * 32;
  }

  for (int t = 0; t < 144; ++t) {      // 9 taps * 16 cb
    int b = t & 3;
    int bs = (t + 3) & 3;
    // gate: tile-t loads retired everywhere after barrier
    if (t <= 141)      asm volatile("s_waitcnt vmcnt(8)" ::: "memory");
    else if (t == 142) asm volatile("s_waitcnt vmcnt(4)" ::: "memory");
    else               asm volatile("s_waitcnt vmcnt(0)" ::: "memory");
    __builtin_amdgcn_s_barrier();
    __builtin_amdgcn_sched_barrier(0);

    const u16* A = smA[b];
    const u16* B = smB[b];

    // ---- issue all 12 fragment reads; order pinned: Af0 | Bf | Af1 ----
    bf16x8 Bf[4], Af0[4], Af1[4];
#pragma unroll
    for (int mi = 0; mi < 4; ++mi)
      Af0[mi] = *(const bf16x8*)&A[(wr * 128 + mi * 16 + lrow) * 32 + prs * 8];
    __builtin_amdgcn_sched_barrier(0);
#pragma unroll
    for (int ni = 0; ni < 4; ++ni)
      Bf[ni] = *(const bf16x8*)&B[(wc * 64 + ni * 16 + lrow) * 32 + prs * 8];
    __builtin_amdgcn_sched_barrier(0);
#pragma unroll
    for (int mi = 0; mi < 4; ++mi)
      Af1[mi] = *(const bf16x8*)&A[(wr * 128 + 64 + mi * 16 + lrow) * 32 + prs * 8];
    __builtin_amdgcn_sched_barrier(0);

    // ---- stage tile t+3 (vmcnt ops only) + pointer advance ----
    if (t <= 140) {
#pragma unroll
      for (int g = 0; g < 2; ++g)
        gl_lds16(rpA[g], &smA[bs][g * 4096 + wv * 512]);
#pragma unroll
      for (int g = 0; g < 2; ++g)
        gl_lds16(rpB[g], &smB[bs][g * 4096 + wv * 512]);
      cb3++;
      if (cb3 == 16) {
        cb3 = 0; tap3++;
#pragma unroll
        for (int g = 0; g < 2; ++g) {
          rpA[g] = srcA_base[g] + (size_t)tap3 * CC;
          rpB[g] = bsrc_for_tap(tap3, g);
        }
      } else {
#pragma unroll
        for (int g = 0; g < 2; ++g) { rpA[g] += 32; rpB[g] += 32; }
      }
    }
    __builtin_amdgcn_sched_barrier(0);

    // ---- per-column pipelined MFMA: column ni needs reads 1..5+ni ----
    __builtin_amdgcn_s_setprio(1);
#pragma unroll
    for (int ni = 0; ni < 4; ++ni) {
      if (ni == 0)      asm volatile("s_waitcnt lgkmcnt(7)" ::: "memory");
      else if (ni == 1) asm volatile("s_waitcnt lgkmcnt(6)" ::: "memory");
      else if (ni == 2) asm volatile("s_waitcnt lgkmcnt(5)" ::: "memory");
      else              asm volatile("s_waitcnt lgkmcnt(4)" ::: "memory");
      __builtin_amdgcn_sched_barrier(0);
#pragma unroll
      for (int mi = 0; mi < 4; ++mi)
        acc0[mi][ni] = __builtin_amdgcn_mfma_f32_16x16x32_bf16(
            Af0[mi], Bf[ni], acc0[mi][ni], 0, 0, 0);
    }

    asm volatile("s_waitcnt lgkmcnt(0)" ::: "memory");
    __builtin_amdgcn_sched_barrier(0);
#pragma unroll
    for (int mi = 0; mi < 4; ++mi)
#pragma unroll
      for (int ni = 0; ni < 4; ++ni)
        acc1[mi][ni] = __builtin_amdgcn_mfma_f32_16x16x32_bf16(
            Af1[mi], Bf[ni], acc1[mi][ni], 0, 0, 0);
    __builtin_amdgcn_s_setprio(0);
  }

  // epilogue: demod scale + bias + noise + LeakyReLU(0.2)
  float ns = nstr[0];
  const float* noise_n = noise + (size_t)n * P_;
  float nz[4];
#pragma unroll
  for (int ni = 0; ni < 4; ++ni)
    nz[ni] = noise_n[pb * 256 + wc * 64 + ni * 16 + lrow] * ns;

  auto epi = [&](f32x4 (&A_)[4][4], int qm) {
#pragma unroll
    for (int mi = 0; mi < 4; ++mi) {
      int o0 = ob * 256 + wr * 128 + qm * 64 + mi * 16 + kgrp * 4;
#pragma unroll
      for (int r = 0; r < 4; ++r) {
        int o = o0 + r;
        float dv = dmod[n * COUT + o];
        float bv = cbias[o];
        float* orow = out + ((size_t)(n * COUT + o)) * P_ + pb * 256 + wc * 64;
#pragma unroll
        for (int ni = 0; ni < 4; ++ni) {
          float v = A_[mi][ni][r] * dv + bv + nz[ni];
          orow[ni * 16 + lrow] = v >= 0.f ? v : 0.2f * v;
        }
      }
    }
  };
  epi(acc0, 0);
  epi(acc1, 1);
}

// ---------- fallback (small ws): direct conv ----------
__global__ __launch_bounds__(64) void k_conv_naive(const float* __restrict__ x,
                                                   const float* __restrict__ cw,
                                                   const float* __restrict__ cbias,
                                                   const float* __restrict__ noise,
                                                   const float* __restrict__ nstr,
                                                   const float* __restrict__ s,
                                                   const float* __restrict__ d,
                                                   float* __restrict__ out) {
  int bid = blockIdx.x;                 // 16*512*64 = (n,o,h)
  int h = bid & 63; int o = (bid >> 6) & 511; int n = bid >> 15;
  int wcol = threadIdx.x;
  float acc = 0.f;
  for (int i = 0; i < CIN; ++i) {
    float sv = s[n * CIN + i];
    const float* xrow = x + ((size_t)(n * CIN + i)) * P_;
    const float* wrp = cw + ((size_t)o * CIN + i) * 9;
#pragma unroll
    for (int t = 0; t < 9; ++t) {
      int hh = h + t / 3 - 1, ww = wcol + t % 3 - 1;
      float xv = ((unsigned)hh < 64u && (unsigned)ww < 64u) ? xrow[hh * 64 + ww] : 0.f;
      acc += xv * sv * wrp[t];
    }
  }
  float v = acc * d[n * COUT + o] + cbias[o] + noise[(size_t)n * P_ + h * 64 + wcol] * nstr[0];
  out[((size_t)(n * COUT + o)) * P_ + h * 64 + wcol] = v >= 0.f ? v : 0.2f * v;
}

extern "C" void kernel_launch(void* const* d_in, const int* in_sizes, int n_in,
                              void* d_out, int out_size, void* d_ws, size_t ws_size,
                              hipStream_t stream) {
  const float* x    = (const float*)d_in[0];
  const float* w    = (const float*)d_in[1];
  const float* noise= (const float*)d_in[2];
  const float* aw   = (const float*)d_in[3];
  const float* ab   = (const float*)d_in[4];
  const float* nstr = (const float*)d_in[5];
  const float* cw   = (const float*)d_in[6];
  const float* cb   = (const float*)d_in[7];
  float* out = (float*)d_out;
  char* ws = (char*)d_ws;
  float* s = (float*)(ws + OFF_S);
  float* d = (float*)(ws + OFF_D);

  k_affine<<<(N_ * COUT) / 256, 256, 0, stream>>>(w, aw, ab, s);
  k_demod<<<COUT, 256, 0, stream>>>(s, cw, d);

  if (ws_size >= WS_NEED) {
    u16* zp  = (u16*)(ws + OFF_Z);
    u16* wbt = (u16*)(ws + OFF_WBT);
    u16* xbb = (u16*)(ws + OFF_XB);
    k_zero<<<1, 256, 0, stream>>>((float*)zp);
    k_wprep<<<(COUT * CIN * 9 + 255) / 256, 256, 0, stream>>>(cw, wbt);
    k_xmod<<<N_ * 8 * 64, 256, 0, stream>>>(x, s, xbb);
    k_conv<<<512, 512, 0, stream>>>(xbb, wbt, zp, d, cb, noise, nstr, out);
  } else {
    k_conv_naive<<<N_ * COUT * 64, 64, 0, stream>>>(x, cw, cb, noise, nstr, s, d, out);
  }
}